// Round 3
// baseline (11990.697 us; speedup 1.0000x reference)
//
#include <hip/hip_runtime.h>
#include <hip/hip_bf16.h>
#include <cstddef>

// ---------------------------------------------------------------------------
// AttentionLSTMDecoder on MI355X.  Round 3: persistent kernel.
//  * q affine in pos -> scores z = p0*a + p1*b + c  (K never materialized)
//  * exp(z) 2nd-order Taylor -> att = ratio of 6 V-moments (V never matd)
//  * Wo folded into W_ih0; [W_ih | W_hh] concatenated -> one K=1088/1024
//    GEMM per layer per step, inputs as cat rows [x|h0], [h0|h1] ping-pong.
//  * ALL 100 steps inside ONE persistent kernel, grid=256 (1 block/CU,
//    co-resident by capacity), custom sense-reversing grid barrier with
//    agent-scope fences between phases (3 barriers/step).
// ---------------------------------------------------------------------------

typedef _Float16 hx8 __attribute__((ext_vector_type(8)));
typedef float fx4 __attribute__((ext_vector_type(4)));

#define NSEQ 640
#define TSTEPS 100
#define XC0 1088   // [x(576) | h0(512)]
#define XC1 1024   // [h0(512) | h1(512)]
#define NBLK 256

__device__ __forceinline__ float sigm(float x){ return 1.0f/(1.0f+__expf(-x)); }
__device__ __forceinline__ float tanh_(float x){
  x = fminf(fmaxf(x, -15.0f), 15.0f);
  float e = __expf(2.0f*x);
  return (e-1.0f)/(e+1.0f);
}
__device__ __forceinline__ float sel4(float a0,float a1,float a2,float a3,int h){
  float r = a0; r = (h==1)?a1:r; r = (h==2)?a2:r; r = (h==3)?a3:r; return r;
}

// ---------------- fold kernels (one-time) ----------------

__global__ void kF1(const float* __restrict__ Wq, const float* __restrict__ Wc,
                    const float* __restrict__ bc, const float* __restrict__ bq,
                    float* __restrict__ u){
  int r = blockIdx.x*256 + threadIdx.x; if (r >= 512) return;
  float s0=0.f, s1=0.f, s2=0.f;
  for (int k=0;k<512;k++){
    float wq = Wq[r*512+k];
    s0 += wq*Wc[k*512+0];
    s1 += wq*Wc[k*512+1];
    s2 += wq*bc[k];
  }
  u[r]=s0; u[512+r]=s1; u[1024+r]=s2+bq[r];
}

__global__ __launch_bounds__(512) void kF2a(const float* __restrict__ Wk,
                                            const float* __restrict__ u,
                                            float* __restrict__ z){
  int ih = blockIdx.x; int kk = threadIdx.x;
  int i = ih>>2, h = ih&3;
  float s = 0.f;
  for (int d=0; d<128; d++)
    s += Wk[(h*128+d)*512 + kk] * u[i*512 + h*128 + d];
  z[ih*512+kk] = s;
}

__global__ __launch_bounds__(512) void kF2b(const float* __restrict__ z,
                                            const float* __restrict__ Wc,
                                            const float* __restrict__ bc,
                                            const float* __restrict__ bk,
                                            const float* __restrict__ u,
                                            float* __restrict__ Y, float* __restrict__ cc){
  const float scale = 0.08838834764831845f; // 1/sqrt(128)
  int ih = blockIdx.x; int j = threadIdx.x;
  int i = ih>>2, h = ih&3;
  float s = 0.f;
  for (int kk=0;kk<512;kk++) s += z[ih*512+kk]*Wc[kk*512+j];
  Y[ih*512+j] = s*scale;
  if (j==0){
    float t=0.f;
    for (int kk=0;kk<512;kk++) t += z[ih*512+kk]*bc[kk];
    for (int d=0;d<128;d++) t += u[i*512+h*128+d]*bk[h*128+d];
    cc[ih] = t*scale;
  }
}

__global__ void kFbv(const float* __restrict__ Wv, const float* __restrict__ bc,
                     const float* __restrict__ bv, float* __restrict__ bv2){
  int r = blockIdx.x*256 + threadIdx.x; if (r >= 512) return;
  float s = bv[r];
  for (int k=0;k<512;k++) s += Wv[r*512+k]*bc[k];
  bv2[r]=s;
}

// fp32 tiled GEMM: C[M,N] = A[:, aoff:aoff+K] @ B (64x64 tiles)
__global__ __launch_bounds__(256) void kgemm(const float* __restrict__ A, int lda, int aoff,
                                             const float* __restrict__ B, int ldb,
                                             float* __restrict__ C, int ldc, int K){
  __shared__ float As[64][16];
  __shared__ float Bs[16][64];
  int tid = threadIdx.x; int tx = tid&15, ty = tid>>4;
  int bx = blockIdx.x, by = blockIdx.y;
  float acc[4][4];
#pragma unroll
  for (int i=0;i<4;i++)
#pragma unroll
    for (int j=0;j<4;j++) acc[i][j]=0.f;
  for (int kk=0; kk<K; kk+=16){
#pragma unroll
    for (int e=0;e<4;e++){
      int id = tid*4+e;
      int r = id>>4, c = id&15;
      As[r][c] = A[(size_t)(by*64+r)*lda + aoff + kk + c];
      int r2 = id>>6, c2 = id&63;
      Bs[r2][c2] = B[(size_t)(kk+r2)*ldb + bx*64 + c2];
    }
    __syncthreads();
#pragma unroll
    for (int k=0;k<16;k++){
      float bvv[4];
#pragma unroll
      for (int j=0;j<4;j++) bvv[j] = Bs[k][tx*4+j];
#pragma unroll
      for (int i=0;i<4;i++){
        float av = As[ty*4+i][k];
#pragma unroll
        for (int j=0;j<4;j++) acc[i][j] += av*bvv[j];
      }
    }
    __syncthreads();
  }
#pragma unroll
  for (int i=0;i<4;i++)
#pragma unroll
    for (int j=0;j<4;j++)
      C[(size_t)(by*64+ty*4+i)*ldc + bx*64+tx*4+j] = acc[i][j];
}

__global__ void ktransp(const float* __restrict__ A, float* __restrict__ AT){
  int idx = blockIdx.x*256 + threadIdx.x;
  int r = idx>>9, c = idx&511;
  AT[c*512 + r] = A[idx];
}

// Bcat0 [2048][1088] = [Wih0[:,0:36] | Wmix | 0pad(28) | Whh0]
__global__ void kbcat0(const float* __restrict__ Wih0, const float* __restrict__ Wmix,
                       const float* __restrict__ Whh0, _Float16* __restrict__ B){
  int r = blockIdx.x;
  for (int c = threadIdx.x; c < 1088; c += 256){
    float v;
    if (c < 36) v = Wih0[r*548 + c];
    else if (c < 548) v = Wmix[r*512 + (c-36)];
    else if (c < 576) v = 0.f;
    else v = Whh0[r*512 + (c-576)];
    B[(size_t)r*1088 + c] = (_Float16)v;
  }
}

// Bcat1 [2048][1024] = [Wih1 | Whh1]
__global__ void kbcat1(const float* __restrict__ Wih1, const float* __restrict__ Whh1,
                       _Float16* __restrict__ B){
  int r = blockIdx.x;
  for (int c = threadIdx.x; c < 1024; c += 256){
    float v = (c < 512) ? Wih1[r*512 + c] : Whh1[r*512 + (c-512)];
    B[(size_t)r*1024 + c] = (_Float16)v;
  }
}

__global__ void kcast(const float* __restrict__ s, _Float16* __restrict__ d, int n){
  int i = blockIdx.x*256 + threadIdx.x;
  if (i < n) d[i] = (_Float16)s[i];
}

// b0 = bih0+bhh0+Wih0[:,36:]@bo ; b1 = bih1+bhh1
__global__ void kbias(const float* __restrict__ Wih0, const float* __restrict__ bo,
                      const float* __restrict__ bih0, const float* __restrict__ bhh0,
                      const float* __restrict__ bih1, const float* __restrict__ bhh1,
                      float* __restrict__ b0, float* __restrict__ b1){
  int j = blockIdx.x*256 + threadIdx.x; if (j >= 2048) return;
  float s = bih0[j]+bhh0[j];
  for (int k=0;k<512;k++) s += Wih0[j*548+36+k]*bo[k];
  b0[j]=s; b1[j]=bih1[j]+bhh1[j];
}

// ---------------- moment precompute ----------------

__global__ __launch_bounds__(256) void kP1(const float* __restrict__ ctx,
                                           const float* __restrict__ Y,
                                           const float* __restrict__ cc,
                                           float* __restrict__ W6){
  __shared__ float Yl[6144];
  __shared__ float ccl[12];
  int tid = threadIdx.x; int n = blockIdx.x;
  for (int e = tid; e < 6144; e += 256) Yl[e] = Y[e];
  if (tid < 12) ccl[tid] = cc[tid];
  __syncthreads();
  int wave = tid >> 6, lane = tid & 63;
  for (int it = 0; it < 50; ++it){
    int s = it*4 + wave;
    const float* cp = ctx + ((size_t)n*200 + s)*512;
    float p[12];
#pragma unroll
    for (int i=0;i<12;i++) p[i]=0.f;
    for (int c8 = 0; c8 < 8; ++c8){
      int col = c8*64 + lane;
      float v = cp[col];
#pragma unroll
      for (int i=0;i<12;i++) p[i] += v * Yl[i*512+col];
    }
#pragma unroll
    for (int m = 32; m; m >>= 1){
#pragma unroll
      for (int i=0;i<12;i++) p[i] += __shfl_xor(p[i], m, 64);
    }
    if (lane < 4){
      int h = lane;
      float a  = sel4(p[0],p[1],p[2], p[3], h) + ccl[h];
      float b  = sel4(p[4],p[5],p[6], p[7], h) + ccl[4+h];
      float cp_= sel4(p[8],p[9],p[10],p[11],h) + ccl[8+h];
      float beta = __expf(cp_);
      size_t base = (size_t)(n*24 + h*6)*200 + s;
      W6[base + 0*200] = beta;
      W6[base + 1*200] = beta*a;
      W6[base + 2*200] = beta*b;
      W6[base + 3*200] = beta*a*a*0.5f;
      W6[base + 4*200] = beta*a*b;
      W6[base + 5*200] = beta*b*b*0.5f;
    }
  }
}

__global__ __launch_bounds__(256) void kP2(const float* __restrict__ ctx,
                                           const float* __restrict__ W6,
                                           float* __restrict__ F, float* __restrict__ S){
  __shared__ float w6[4800];
  int tid = threadIdx.x, n = blockIdx.x;
  for (int e = tid; e < 4800; e += 256) w6[e] = W6[(size_t)n*4800 + e];
  __syncthreads();
  float a0[24], a1[24];
#pragma unroll
  for (int r=0;r<24;r++){ a0[r]=0.f; a1[r]=0.f; }
  const float* cp = ctx + (size_t)n*200*512;
  for (int s=0;s<200;s++){
    float v0 = cp[s*512 + tid];
    float v1 = cp[s*512 + tid + 256];
#pragma unroll
    for (int r=0;r<24;r++){ float w = w6[r*200+s]; a0[r]+=w*v0; a1[r]+=w*v1; }
  }
#pragma unroll
  for (int r=0;r<24;r++){
    F[(size_t)(n*24+r)*512 + tid]       = a0[r];
    F[(size_t)(n*24+r)*512 + tid + 256] = a1[r];
  }
  if (tid < 24){
    float s=0.f;
    for (int ss=0; ss<200; ss++) s += w6[tid*200+ss];
    S[n*24+tid]=s;
  }
}

__global__ __launch_bounds__(128) void kP3(const float* __restrict__ F,
                                           const float* __restrict__ WcvT,
                                           float* __restrict__ M){
  __shared__ float Fl[3072];
  int tid = threadIdx.x; int b = blockIdx.x; int n = b>>2, h = b&3;
  for (int e = tid; e < 3072; e += 128) Fl[e] = F[(size_t)(n*24 + h*6)*512 + e];
  __syncthreads();
  float acc[6];
#pragma unroll
  for (int i=0;i<6;i++) acc[i]=0.f;
  for (int k=0;k<512;k++){
    float w = WcvT[k*512 + h*128 + tid];
#pragma unroll
    for (int i=0;i<6;i++) acc[i] += w * Fl[i*512+k];
  }
#pragma unroll
  for (int i=0;i<6;i++) M[(size_t)(n*24+h*6+i)*128 + tid] = acc[i];
}

// ---------------- state init ----------------

__global__ __launch_bounds__(512) void kinit(const float* __restrict__ ball,
                    const int* __restrict__ roles, const float* __restrict__ remb,
                    _Float16* __restrict__ x0, _Float16* __restrict__ x1,
                    _Float16* __restrict__ hc0, _Float16* __restrict__ hc1,
                    float* __restrict__ c0, float* __restrict__ c1){
  int n = blockIdx.x, tid = threadIdx.x;
  int b = n/10;
  int role = roles[n];
  for (int c = tid; c < XC0; c += 512){
    float v = 0.f;
    if (c>=2 && c<4)       v = ball[b*2 + (c-2)];
    else if (c>=4 && c<36) v = remb[role*32 + (c-4)];
    _Float16 hv = (_Float16)v;
    x0[(size_t)n*XC0+c] = hv;
    x1[(size_t)n*XC0+c] = hv;
  }
  for (int c = tid; c < XC1; c += 512){
    hc0[(size_t)n*XC1+c] = (_Float16)0.f;
    hc1[(size_t)n*XC1+c] = (_Float16)0.f;
  }
  if (tid < 512){
    c0[n*512+tid]=0.f; c1[n*512+tid]=0.f;
  }
}

__global__ __launch_bounds__(128) void katt0(const float* __restrict__ ipos,
                                             const float* __restrict__ M,
                                             const float* __restrict__ S,
                                             const float* __restrict__ bv2,
                                             _Float16* __restrict__ x){
  int n = blockIdx.x, tid = threadIdx.x;
  float p0 = ipos[n*2], p1 = ipos[n*2+1];
  if (tid==0){ x[(size_t)n*XC0]=(_Float16)p0; x[(size_t)n*XC0+1]=(_Float16)p1; }
  float fa=p0*p0, fb=p0*p1, fc=p1*p1;
  for (int hd = tid; hd < 512; hd += 128){
    int h = hd>>7;
    int sb = n*24 + h*6;
    float den = S[sb] + p0*S[sb+1] + p1*S[sb+2] + fa*S[sb+3] + fb*S[sb+4] + fc*S[sb+5];
    const float* mp = M + (size_t)sb*128 + (hd&127);
    float num = mp[0] + p0*mp[128] + p1*mp[256] + fa*mp[384] + fb*mp[512] + fc*mp[640];
    x[(size_t)n*XC0 + 36 + hd] = (_Float16)(num/den + bv2[hd]);
  }
}

// ---------------- persistent loop kernel ----------------

struct KA {
  const _Float16 *hB0, *hB1, *hWf1;
  const float *fb0, *fb1, *bf1, *Wf2, *bf2, *fM, *fS, *fbv2;
  float *fc0, *fc1, *out;
  _Float16 *xc0, *xc1, *hc0, *hc1;
  unsigned *bar;
};

// sense-reversing grid barrier; agent-scope fences give cross-XCD visibility
__device__ __forceinline__ void gridbar(unsigned* cnt, unsigned* gen){
  __syncthreads();
  if (threadIdx.x == 0){
    __builtin_amdgcn_fence(__ATOMIC_RELEASE, "agent");
    unsigned g = __hip_atomic_load(gen, __ATOMIC_RELAXED, __HIP_MEMORY_SCOPE_AGENT);
    unsigned a = __hip_atomic_fetch_add(cnt, 1u, __ATOMIC_RELAXED, __HIP_MEMORY_SCOPE_AGENT);
    if (a == NBLK-1u){
      __hip_atomic_store(cnt, 0u, __ATOMIC_RELAXED, __HIP_MEMORY_SCOPE_AGENT);
      __hip_atomic_store(gen, g+1u, __ATOMIC_RELEASE, __HIP_MEMORY_SCOPE_AGENT);
    } else {
      while (__hip_atomic_load(gen, __ATOMIC_RELAXED, __HIP_MEMORY_SCOPE_AGENT) == g)
        __builtin_amdgcn_s_sleep(2);
    }
    __builtin_amdgcn_fence(__ATOMIC_ACQUIRE, "agent");
  }
  __syncthreads();
}

// One layer: gates = [A | Acat] @ Bcat^T + bias, fused LSTM.
// 256 blocks = 8 mblk (80 rows) x 32 jb (16 cols/gate); 4 waves = 4 gates.
__device__ __forceinline__ void gates_phase(
    const _Float16* __restrict__ A, int lda, int nc, const _Float16* __restrict__ B,
    const float* __restrict__ bias, float* __restrict__ cst,
    _Float16* __restrict__ h1p, int ldh1, int co1,
    _Float16* __restrict__ h2p, int ldh2, int co2,
    _Float16 (*sbuf)[10368], float (*eps)[80][17])
{
  int tid = threadIdx.x, w = tid>>6, lane = tid&63;
  int lr = lane&15, lq = lane>>4;
  int bx = blockIdx.x, mblk = bx>>5, jb = bx&31;
  int m0 = mblk*80, j0 = jb*16;

  // A tile: 80 rows x 64 halves = 640 ids (row=id>>3, c8=id&7); 2-3 per thread
  int tA1 = tid + 256, tA2 = tid + 512;
  bool hasA2 = tA2 < 640;
  const _Float16* gA0 = A + (size_t)(m0 + (tid>>3))*lda + (tid&7)*8;
  const _Float16* gA1 = A + (size_t)(m0 + (tA1>>3))*lda + (tA1&7)*8;
  const _Float16* gA2 = A + (size_t)(m0 + ((hasA2?tA2:0)>>3))*lda + (tA2&7)*8;
  int sA0 = (tid>>3)*72 + (tid&7)*8;
  int sA1 = (tA1>>3)*72 + (tA1&7)*8;
  int sA2 = (tA2>>3)*72 + (tA2&7)*8;
  // B tile: 64 rows (4 gates x 16 cols) x 64 halves = 512 ids; 2 per thread
  int rB0 = tid>>3, rB1 = (tid+256)>>3;
  const _Float16* gB0 = B + (size_t)((rB0>>4)*512 + j0 + (rB0&15))*lda + (tid&7)*8;
  const _Float16* gB1 = B + (size_t)((rB1>>4)*512 + j0 + (rB1&15))*lda + (tid&7)*8;
  int sB0 = 5760 + rB0*72 + (tid&7)*8;
  int sB1 = 5760 + rB1*72 + (tid&7)*8;

  hx8 rA0v = *(const hx8*)gA0;
  hx8 rA1v = *(const hx8*)gA1;
  hx8 rA2v = hasA2 ? *(const hx8*)gA2 : hx8{};
  hx8 rB0v = *(const hx8*)gB0;
  hx8 rB1v = *(const hx8*)gB1;

  fx4 ac[5];
#pragma unroll
  for (int s=0;s<5;s++) ac[s] = fx4{0.f,0.f,0.f,0.f};

  for (int c=0; c<nc; ++c){
    _Float16* sb = sbuf[c&1];
    *(hx8*)(sb+sA0) = rA0v;
    *(hx8*)(sb+sA1) = rA1v;
    if (hasA2) *(hx8*)(sb+sA2) = rA2v;
    *(hx8*)(sb+sB0) = rB0v;
    *(hx8*)(sb+sB1) = rB1v;
    __syncthreads();
    if (c+1 < nc){
      int k = (c+1)*64;
      rA0v = *(const hx8*)(gA0+k);
      rA1v = *(const hx8*)(gA1+k);
      if (hasA2) rA2v = *(const hx8*)(gA2+k);
      rB0v = *(const hx8*)(gB0+k);
      rB1v = *(const hx8*)(gB1+k);
    }
    const _Float16* bp = sb + 5760 + (w*16+lr)*72 + lq*8;
    hx8 b0 = *(const hx8*)bp;
    hx8 b1 = *(const hx8*)(bp+32);
#pragma unroll
    for (int s=0;s<5;s++){
      hx8 a0 = *(const hx8*)(sb + (s*16+lr)*72 + lq*8);
      ac[s] = __builtin_amdgcn_mfma_f32_16x16x32_f16(a0, b0, ac[s], 0,0,0);
    }
#pragma unroll
    for (int s=0;s<5;s++){
      hx8 a1 = *(const hx8*)(sb + (s*16+lr)*72 + lq*8 + 32);
      ac[s] = __builtin_amdgcn_mfma_f32_16x16x32_f16(a1, b1, ac[s], 0,0,0);
    }
  }
#pragma unroll
  for (int s=0;s<5;s++)
#pragma unroll
    for (int r=0;r<4;r++)
      eps[w][s*16+lq*4+r][lr] = ac[s][r];
  __syncthreads();
#pragma unroll
  for (int e=0;e<5;e++){
    int idx = e*256 + tid;
    int ml = idx>>4, j = idx&15;
    float gi = eps[0][ml][j] + bias[       j0+j];
    float gf = eps[1][ml][j] + bias[ 512 + j0+j];
    float gg = eps[2][ml][j] + bias[1024 + j0+j];
    float go = eps[3][ml][j] + bias[1536 + j0+j];
    int ci = (m0+ml)*512 + j0 + j;
    float c_ = cst[ci];
    float cn = sigm(gf)*c_ + sigm(gi)*tanh_(gg);
    float hn = sigm(go)*tanh_(cn);
    cst[ci] = cn;
    _Float16 hh = (_Float16)hn;
    h1p[(size_t)(m0+ml)*ldh1 + co1 + j0 + j] = hh;
    if (h2p) h2p[(size_t)(m0+ml)*ldh2 + co2 + j0 + j] = hh;
  }
}

// head (Wf1/relu/Wf2) + next-step attention; blocks 0..39, 16 rows each
__device__ __forceinline__ void head_phase(const _Float16* __restrict__ h1,
    const _Float16* __restrict__ Wf1, const float* __restrict__ bf1,
    const float* __restrict__ Wf2, const float* __restrict__ bf2,
    const float* __restrict__ M, const float* __restrict__ S,
    const float* __restrict__ bv2, _Float16* __restrict__ xn,
    float* __restrict__ out, int t,
    float* hidp, float (*posL)[2], float (*denL)[4])
{
  int tid = threadIdx.x, w = tid>>6, lane = tid&63;
  int lr = lane&15, lq = lane>>4;
  int n0 = blockIdx.x*16;
  fx4 a0=fx4{0.f,0.f,0.f,0.f}, a1=a0, a2=a0, a3=a0;
  {
    const _Float16* ap  = h1 + (size_t)(n0+lr)*XC1 + lq*8;
    const _Float16* bp0 = Wf1 + (size_t)(w*64 + lr)*512 + lq*8;
    const _Float16* bp1 = bp0 + 16*512;
    const _Float16* bp2 = bp0 + 32*512;
    const _Float16* bp3 = bp0 + 48*512;
    for (int ks=0; ks<16; ks++){
      int k = ks*32;
      hx8 a = *(const hx8*)(ap + k);
      a0 = __builtin_amdgcn_mfma_f32_16x16x32_f16(a, *(const hx8*)(bp0+k), a0, 0,0,0);
      a1 = __builtin_amdgcn_mfma_f32_16x16x32_f16(a, *(const hx8*)(bp1+k), a1, 0,0,0);
      a2 = __builtin_amdgcn_mfma_f32_16x16x32_f16(a, *(const hx8*)(bp2+k), a2, 0,0,0);
      a3 = __builtin_amdgcn_mfma_f32_16x16x32_f16(a, *(const hx8*)(bp3+k), a3, 0,0,0);
    }
  }
#pragma unroll
  for (int r=0;r<4;r++){
    int row = lq*4+r;
    hidp[row*264 + w*64 +  0 + lr] = fmaxf(a0[r] + bf1[w*64 +  0 + lr], 0.f);
    hidp[row*264 + w*64 + 16 + lr] = fmaxf(a1[r] + bf1[w*64 + 16 + lr], 0.f);
    hidp[row*264 + w*64 + 32 + lr] = fmaxf(a2[r] + bf1[w*64 + 32 + lr], 0.f);
    hidp[row*264 + w*64 + 48 + lr] = fmaxf(a3[r] + bf1[w*64 + 48 + lr], 0.f);
  }
  __syncthreads();
  {
    int nn = tid>>4, o = (tid>>3)&1, sub = tid&7;
    float s = 0.f;
    for (int k2=0;k2<32;k2++) s += hidp[nn*264 + k2*8 + sub] * Wf2[o*256 + k2*8 + sub];
    s += __shfl_xor(s, 1, 64);
    s += __shfl_xor(s, 2, 64);
    s += __shfl_xor(s, 4, 64);
    if (sub==0){
      s += bf2[o];
      out[((size_t)(n0+nn)*TSTEPS + t)*2 + o] = s;
      posL[nn][o] = s;
      xn[(size_t)(n0+nn)*XC0 + o] = (_Float16)s;
    }
  }
  __syncthreads();
  if (tid < 64){
    int nn = tid>>2, h = tid&3;
    float p0 = posL[nn][0], p1 = posL[nn][1];
    int sb = (n0+nn)*24 + h*6;
    float den = S[sb] + p0*S[sb+1] + p1*S[sb+2] + p0*p0*S[sb+3] + p0*p1*S[sb+4] + p1*p1*S[sb+5];
    denL[nn][h] = 1.0f/den;
  }
  __syncthreads();
  for (int nn=0; nn<16; nn++){
    float p0 = posL[nn][0], p1 = posL[nn][1];
    float fa = p0*p0, fb = p0*p1, fcx = p1*p1;
#pragma unroll
    for (int r=0;r<2;r++){
      int hd = r*256 + tid;
      int h = hd>>7;
      const float* mp = M + (size_t)((n0+nn)*24 + h*6)*128 + (hd&127);
      float num = mp[0] + p0*mp[128] + p1*mp[256] + fa*mp[384] + fb*mp[512] + fcx*mp[640];
      xn[(size_t)(n0+nn)*XC0 + 36 + hd] = (_Float16)(num*denL[nn][h] + bv2[hd]);
    }
  }
}

__global__ __launch_bounds__(256) void kloop(KA a){
  __shared__ _Float16 sbuf[2][10368];  // A 80x72 @0, B 64x72 @5760 (halves)
  __shared__ float eps[4][80][17];     // gate exchange; head reuses as hid
  __shared__ float posL[16][2];
  __shared__ float denL[16][4];
  unsigned* cnt = a.bar;
  unsigned* gen = a.bar + 1;
  for (int t = 0; t < TSTEPS; ++t){
    _Float16* xin = (t&1) ? a.xc1 : a.xc0;
    _Float16* xnx = (t&1) ? a.xc0 : a.xc1;
    _Float16* hin = (t&1) ? a.hc1 : a.hc0;
    _Float16* hnx = (t&1) ? a.hc0 : a.hc1;
    gates_phase(xin, XC0, 17, a.hB0, a.fb0, a.fc0,
                hin, XC1, 0, xnx, XC0, 576, sbuf, eps);
    gridbar(cnt, gen);
    gates_phase(hin, XC1, 16, a.hB1, a.fb1, a.fc1,
                hnx, XC1, 512, (_Float16*)nullptr, 0, 0, sbuf, eps);
    gridbar(cnt, gen);
    if (blockIdx.x < 40)
      head_phase(hnx + 512, a.hWf1, a.bf1, a.Wf2, a.bf2, a.fM, a.fS, a.fbv2,
                 xnx, a.out, t, &eps[0][0][0], posL, denL);
    gridbar(cnt, gen);
  }
}

// ---------------------------------------------------------------------------

extern "C" void kernel_launch(void* const* d_in, const int* in_sizes, int n_in,
                              void* d_out, int out_size, void* d_ws, size_t ws_size,
                              hipStream_t stream) {
  const float* ctx   = (const float*)d_in[0];
  const float* ipos  = (const float*)d_in[1];
  const float* ball  = (const float*)d_in[2];
  const int*   roles = (const int*)  d_in[3];
  const float* remb  = (const float*)d_in[5];
  const float* Wc    = (const float*)d_in[6];
  const float* bc    = (const float*)d_in[7];
  const float* Wq    = (const float*)d_in[8];
  const float* bq    = (const float*)d_in[9];
  const float* Wk    = (const float*)d_in[10];
  const float* bk    = (const float*)d_in[11];
  const float* Wv    = (const float*)d_in[12];
  const float* bv    = (const float*)d_in[13];
  const float* Wo    = (const float*)d_in[14];
  const float* bo    = (const float*)d_in[15];
  const float* Wih0  = (const float*)d_in[16];
  const float* Whh0  = (const float*)d_in[17];
  const float* bih0  = (const float*)d_in[18];
  const float* bhh0  = (const float*)d_in[19];
  const float* Wih1  = (const float*)d_in[20];
  const float* Whh1  = (const float*)d_in[21];
  const float* bih1  = (const float*)d_in[22];
  const float* bhh1  = (const float*)d_in[23];
  const float* Wf1   = (const float*)d_in[24];
  const float* bf1   = (const float*)d_in[25];
  const float* Wf2   = (const float*)d_in[26];
  const float* bf2   = (const float*)d_in[27];
  float* out = (float*)d_out;

  char* w = (char*)d_ws;
  auto alloc = [&](size_t bytes){ void* p = (void*)w; w += (bytes + 255) & ~(size_t)255; return p; };
  float* fY    = (float*)alloc(12*512*4);
  float* fcc   = (float*)alloc(12*4);
  float* fu    = (float*)alloc(3*512*4);
  float* fz    = (float*)alloc(12*512*4);
  float* fbv2  = (float*)alloc(512*4);
  float* fWcv  = (float*)alloc((size_t)512*512*4);
  float* fWcvT = (float*)alloc((size_t)512*512*4);
  float* fWmix = (float*)alloc((size_t)2048*512*4);
  _Float16* hB0  = (_Float16*)alloc((size_t)2048*XC0*2);
  _Float16* hB1  = (_Float16*)alloc((size_t)2048*XC1*2);
  _Float16* hWf1 = (_Float16*)alloc((size_t)256*512*2);
  float* fb0 = (float*)alloc(2048*4);
  float* fb1 = (float*)alloc(2048*4);
  float* fW6 = (float*)alloc((size_t)NSEQ*24*200*4);
  float* fS  = (float*)alloc((size_t)NSEQ*24*4);
  float* fF  = (float*)alloc((size_t)NSEQ*24*512*4);
  float* fM  = (float*)alloc((size_t)NSEQ*24*128*4);
  _Float16* xc0 = (_Float16*)alloc((size_t)NSEQ*XC0*2);
  _Float16* xc1 = (_Float16*)alloc((size_t)NSEQ*XC0*2);
  _Float16* hc0 = (_Float16*)alloc((size_t)NSEQ*XC1*2);
  _Float16* hc1 = (_Float16*)alloc((size_t)NSEQ*XC1*2);
  float* fc0 = (float*)alloc((size_t)NSEQ*512*4);
  float* fc1 = (float*)alloc((size_t)NSEQ*512*4);
  unsigned* bar = (unsigned*)alloc(256);

  // ---- folds ----
  kF1 <<<2,  256, 0, stream>>>(Wq, Wc, bc, bq, fu);
  kF2a<<<12, 512, 0, stream>>>(Wk, fu, fz);
  kF2b<<<12, 512, 0, stream>>>(fz, Wc, bc, bk, fu, fY, fcc);
  kFbv<<<2,  256, 0, stream>>>(Wv, bc, bv, fbv2);
  kgemm<<<dim3(8,8),  256, 0, stream>>>(Wv,   512, 0,  Wc, 512, fWcv,  512, 512);
  ktransp<<<1024, 256, 0, stream>>>(fWcv, fWcvT);
  kgemm<<<dim3(8,32), 256, 0, stream>>>(Wih0, 548, 36, Wo, 512, fWmix, 512, 512);
  kbcat0<<<2048, 256, 0, stream>>>(Wih0, fWmix, Whh0, hB0);
  kbcat1<<<2048, 256, 0, stream>>>(Wih1, Whh1, hB1);
  kcast<<<512,  256, 0, stream>>>(Wf1, hWf1, 256*512);
  kbias<<<8, 256, 0, stream>>>(Wih0, bo, bih0, bhh0, bih1, bhh1, fb0, fb1);

  // ---- moments ----
  kP1<<<NSEQ, 256, 0, stream>>>(ctx, fY, fcc, fW6);
  kP2<<<NSEQ, 256, 0, stream>>>(ctx, fW6, fF, fS);
  kP3<<<NSEQ*4, 128, 0, stream>>>(fF, fWcvT, fM);

  // ---- state init ----
  kinit<<<NSEQ, 512, 0, stream>>>(ball, roles, remb, xc0, xc1, hc0, hc1, fc0, fc1);
  katt0<<<NSEQ, 128, 0, stream>>>(ipos, fM, fS, fbv2, xc0);

  // ---- persistent recurrent loop (ws is poisoned before each call) ----
  hipMemsetAsync(bar, 0, 8, stream);
  KA ka;
  ka.hB0=hB0; ka.hB1=hB1; ka.hWf1=hWf1;
  ka.fb0=fb0; ka.fb1=fb1; ka.bf1=bf1; ka.Wf2=Wf2; ka.bf2=bf2;
  ka.fM=fM; ka.fS=fS; ka.fbv2=fbv2;
  ka.fc0=fc0; ka.fc1=fc1; ka.out=out;
  ka.xc0=xc0; ka.xc1=xc1; ka.hc0=hc0; ka.hc1=hc1;
  ka.bar=bar;
  kloop<<<NBLK, 256, 0, stream>>>(ka);
}

// Round 4
// 9295.837 us; speedup vs baseline: 1.2899x; 1.2899x over previous
//
#include <hip/hip_runtime.h>
#include <hip/hip_bf16.h>
#include <cstddef>

// ---------------------------------------------------------------------------
// AttentionLSTMDecoder on MI355X.  Round 4: persistent kernel, fence-free.
//  * q affine in pos -> scores z = p0*a + p1*b + c  (K never materialized)
//  * exp(z) 2nd-order Taylor -> att = ratio of 6 V-moments (V never matd)
//  * Wo folded into W_ih0; [W_ih | W_hh] concatenated per layer.
//  * ONE persistent kernel for all 100 steps; grid barrier uses a MONOTONIC
//    relaxed agent-scope counter (NO acquire/release fences -> L2 never
//    flushed; weights stay L2-hot). Cross-block activations move through
//    L3 via relaxed agent-scope atomic dword loads/stores (sc0 sc1).
// ---------------------------------------------------------------------------

typedef _Float16 hx8 __attribute__((ext_vector_type(8)));
typedef float fx4 __attribute__((ext_vector_type(4)));
typedef unsigned ux4 __attribute__((ext_vector_type(4)));

#define NSEQ 640
#define TSTEPS 100
#define XC0 1088   // [x(576) | h0(512)]
#define XC1 1024   // [h0(512) | h1(512)]
#define NBLK 256

__device__ __forceinline__ float sigm(float x){ return 1.0f/(1.0f+__expf(-x)); }
__device__ __forceinline__ float tanh_(float x){
  x = fminf(fmaxf(x, -15.0f), 15.0f);
  float e = __expf(2.0f*x);
  return (e-1.0f)/(e+1.0f);
}
__device__ __forceinline__ float sel4(float a0,float a1,float a2,float a3,int h){
  float r = a0; r = (h==1)?a1:r; r = (h==2)?a2:r; r = (h==3)?a3:r; return r;
}

// relaxed agent-scope dword access: sc0 sc1 (bypass L1/L2, coherent at L3)
__device__ __forceinline__ unsigned ald(const unsigned* p){
  return __hip_atomic_load(p, __ATOMIC_RELAXED, __HIP_MEMORY_SCOPE_AGENT);
}
__device__ __forceinline__ void ast(unsigned* p, unsigned v){
  __hip_atomic_store(p, v, __ATOMIC_RELAXED, __HIP_MEMORY_SCOPE_AGENT);
}
__device__ __forceinline__ unsigned packh(float a, float b){
  unsigned short ua = __builtin_bit_cast(unsigned short, (_Float16)a);
  unsigned short ub = __builtin_bit_cast(unsigned short, (_Float16)b);
  return (unsigned)ua | ((unsigned)ub<<16);
}

// ---------------- fold kernels (one-time) ----------------

__global__ void kF1(const float* __restrict__ Wq, const float* __restrict__ Wc,
                    const float* __restrict__ bc, const float* __restrict__ bq,
                    float* __restrict__ u){
  int r = blockIdx.x*256 + threadIdx.x; if (r >= 512) return;
  float s0=0.f, s1=0.f, s2=0.f;
  for (int k=0;k<512;k++){
    float wq = Wq[r*512+k];
    s0 += wq*Wc[k*512+0];
    s1 += wq*Wc[k*512+1];
    s2 += wq*bc[k];
  }
  u[r]=s0; u[512+r]=s1; u[1024+r]=s2+bq[r];
}

__global__ __launch_bounds__(512) void kF2a(const float* __restrict__ Wk,
                                            const float* __restrict__ u,
                                            float* __restrict__ z){
  int ih = blockIdx.x; int kk = threadIdx.x;
  int i = ih>>2, h = ih&3;
  float s = 0.f;
  for (int d=0; d<128; d++)
    s += Wk[(h*128+d)*512 + kk] * u[i*512 + h*128 + d];
  z[ih*512+kk] = s;
}

__global__ __launch_bounds__(512) void kF2b(const float* __restrict__ z,
                                            const float* __restrict__ Wc,
                                            const float* __restrict__ bc,
                                            const float* __restrict__ bk,
                                            const float* __restrict__ u,
                                            float* __restrict__ Y, float* __restrict__ cc){
  const float scale = 0.08838834764831845f; // 1/sqrt(128)
  int ih = blockIdx.x; int j = threadIdx.x;
  int i = ih>>2, h = ih&3;
  float s = 0.f;
  for (int kk=0;kk<512;kk++) s += z[ih*512+kk]*Wc[kk*512+j];
  Y[ih*512+j] = s*scale;
  if (j==0){
    float t=0.f;
    for (int kk=0;kk<512;kk++) t += z[ih*512+kk]*bc[kk];
    for (int d=0;d<128;d++) t += u[i*512+h*128+d]*bk[h*128+d];
    cc[ih] = t*scale;
  }
}

__global__ void kFbv(const float* __restrict__ Wv, const float* __restrict__ bc,
                     const float* __restrict__ bv, float* __restrict__ bv2){
  int r = blockIdx.x*256 + threadIdx.x; if (r >= 512) return;
  float s = bv[r];
  for (int k=0;k<512;k++) s += Wv[r*512+k]*bc[k];
  bv2[r]=s;
}

__global__ __launch_bounds__(256) void kgemm(const float* __restrict__ A, int lda, int aoff,
                                             const float* __restrict__ B, int ldb,
                                             float* __restrict__ C, int ldc, int K){
  __shared__ float As[64][16];
  __shared__ float Bs[16][64];
  int tid = threadIdx.x; int tx = tid&15, ty = tid>>4;
  int bx = blockIdx.x, by = blockIdx.y;
  float acc[4][4];
#pragma unroll
  for (int i=0;i<4;i++)
#pragma unroll
    for (int j=0;j<4;j++) acc[i][j]=0.f;
  for (int kk=0; kk<K; kk+=16){
#pragma unroll
    for (int e=0;e<4;e++){
      int id = tid*4+e;
      int r = id>>4, c = id&15;
      As[r][c] = A[(size_t)(by*64+r)*lda + aoff + kk + c];
      int r2 = id>>6, c2 = id&63;
      Bs[r2][c2] = B[(size_t)(kk+r2)*ldb + bx*64 + c2];
    }
    __syncthreads();
#pragma unroll
    for (int k=0;k<16;k++){
      float bvv[4];
#pragma unroll
      for (int j=0;j<4;j++) bvv[j] = Bs[k][tx*4+j];
#pragma unroll
      for (int i=0;i<4;i++){
        float av = As[ty*4+i][k];
#pragma unroll
        for (int j=0;j<4;j++) acc[i][j] += av*bvv[j];
      }
    }
    __syncthreads();
  }
#pragma unroll
  for (int i=0;i<4;i++)
#pragma unroll
    for (int j=0;j<4;j++)
      C[(size_t)(by*64+ty*4+i)*ldc + bx*64+tx*4+j] = acc[i][j];
}

__global__ void ktransp(const float* __restrict__ A, float* __restrict__ AT){
  int idx = blockIdx.x*256 + threadIdx.x;
  int r = idx>>9, c = idx&511;
  AT[c*512 + r] = A[idx];
}

__global__ void kbcat0(const float* __restrict__ Wih0, const float* __restrict__ Wmix,
                       const float* __restrict__ Whh0, _Float16* __restrict__ B){
  int r = blockIdx.x;
  for (int c = threadIdx.x; c < 1088; c += 256){
    float v;
    if (c < 36) v = Wih0[r*548 + c];
    else if (c < 548) v = Wmix[r*512 + (c-36)];
    else if (c < 576) v = 0.f;
    else v = Whh0[r*512 + (c-576)];
    B[(size_t)r*1088 + c] = (_Float16)v;
  }
}

__global__ void kbcat1(const float* __restrict__ Wih1, const float* __restrict__ Whh1,
                       _Float16* __restrict__ B){
  int r = blockIdx.x;
  for (int c = threadIdx.x; c < 1024; c += 256){
    float v = (c < 512) ? Wih1[r*512 + c] : Whh1[r*512 + (c-512)];
    B[(size_t)r*1024 + c] = (_Float16)v;
  }
}

__global__ void kcast(const float* __restrict__ s, _Float16* __restrict__ d, int n){
  int i = blockIdx.x*256 + threadIdx.x;
  if (i < n) d[i] = (_Float16)s[i];
}

__global__ void kbias(const float* __restrict__ Wih0, const float* __restrict__ bo,
                      const float* __restrict__ bih0, const float* __restrict__ bhh0,
                      const float* __restrict__ bih1, const float* __restrict__ bhh1,
                      float* __restrict__ b0, float* __restrict__ b1){
  int j = blockIdx.x*256 + threadIdx.x; if (j >= 2048) return;
  float s = bih0[j]+bhh0[j];
  for (int k=0;k<512;k++) s += Wih0[j*548+36+k]*bo[k];
  b0[j]=s; b1[j]=bih1[j]+bhh1[j];
}

// ---------------- moment precompute ----------------

__global__ __launch_bounds__(256) void kP1(const float* __restrict__ ctx,
                                           const float* __restrict__ Y,
                                           const float* __restrict__ cc,
                                           float* __restrict__ W6){
  __shared__ float Yl[6144];
  __shared__ float ccl[12];
  int tid = threadIdx.x; int n = blockIdx.x;
  for (int e = tid; e < 6144; e += 256) Yl[e] = Y[e];
  if (tid < 12) ccl[tid] = cc[tid];
  __syncthreads();
  int wave = tid >> 6, lane = tid & 63;
  for (int it = 0; it < 50; ++it){
    int s = it*4 + wave;
    const float* cp = ctx + ((size_t)n*200 + s)*512;
    float p[12];
#pragma unroll
    for (int i=0;i<12;i++) p[i]=0.f;
    for (int c8 = 0; c8 < 8; ++c8){
      int col = c8*64 + lane;
      float v = cp[col];
#pragma unroll
      for (int i=0;i<12;i++) p[i] += v * Yl[i*512+col];
    }
#pragma unroll
    for (int m = 32; m; m >>= 1){
#pragma unroll
      for (int i=0;i<12;i++) p[i] += __shfl_xor(p[i], m, 64);
    }
    if (lane < 4){
      int h = lane;
      float a  = sel4(p[0],p[1],p[2], p[3], h) + ccl[h];
      float b  = sel4(p[4],p[5],p[6], p[7], h) + ccl[4+h];
      float cp_= sel4(p[8],p[9],p[10],p[11],h) + ccl[8+h];
      float beta = __expf(cp_);
      size_t base = (size_t)(n*24 + h*6)*200 + s;
      W6[base + 0*200] = beta;
      W6[base + 1*200] = beta*a;
      W6[base + 2*200] = beta*b;
      W6[base + 3*200] = beta*a*a*0.5f;
      W6[base + 4*200] = beta*a*b;
      W6[base + 5*200] = beta*b*b*0.5f;
    }
  }
}

__global__ __launch_bounds__(256) void kP2(const float* __restrict__ ctx,
                                           const float* __restrict__ W6,
                                           float* __restrict__ F, float* __restrict__ S){
  __shared__ float w6[4800];
  int tid = threadIdx.x, n = blockIdx.x;
  for (int e = tid; e < 4800; e += 256) w6[e] = W6[(size_t)n*4800 + e];
  __syncthreads();
  float a0[24], a1[24];
#pragma unroll
  for (int r=0;r<24;r++){ a0[r]=0.f; a1[r]=0.f; }
  const float* cp = ctx + (size_t)n*200*512;
  for (int s=0;s<200;s++){
    float v0 = cp[s*512 + tid];
    float v1 = cp[s*512 + tid + 256];
#pragma unroll
    for (int r=0;r<24;r++){ float w = w6[r*200+s]; a0[r]+=w*v0; a1[r]+=w*v1; }
  }
#pragma unroll
  for (int r=0;r<24;r++){
    F[(size_t)(n*24+r)*512 + tid]       = a0[r];
    F[(size_t)(n*24+r)*512 + tid + 256] = a1[r];
  }
  if (tid < 24){
    float s=0.f;
    for (int ss=0; ss<200; ss++) s += w6[tid*200+ss];
    S[n*24+tid]=s;
  }
}

__global__ __launch_bounds__(128) void kP3(const float* __restrict__ F,
                                           const float* __restrict__ WcvT,
                                           float* __restrict__ M){
  __shared__ float Fl[3072];
  int tid = threadIdx.x; int b = blockIdx.x; int n = b>>2, h = b&3;
  for (int e = tid; e < 3072; e += 128) Fl[e] = F[(size_t)(n*24 + h*6)*512 + e];
  __syncthreads();
  float acc[6];
#pragma unroll
  for (int i=0;i<6;i++) acc[i]=0.f;
  for (int k=0;k<512;k++){
    float w = WcvT[k*512 + h*128 + tid];
#pragma unroll
    for (int i=0;i<6;i++) acc[i] += w * Fl[i*512+k];
  }
#pragma unroll
  for (int i=0;i<6;i++) M[(size_t)(n*24+h*6+i)*128 + tid] = acc[i];
}

// ---------------- state init ----------------

__global__ __launch_bounds__(512) void kinit(const float* __restrict__ ball,
                    const int* __restrict__ roles, const float* __restrict__ remb,
                    _Float16* __restrict__ x0, _Float16* __restrict__ x1,
                    _Float16* __restrict__ hc0, _Float16* __restrict__ hc1,
                    float* __restrict__ c0, float* __restrict__ c1){
  int n = blockIdx.x, tid = threadIdx.x;
  int b = n/10;
  int role = roles[n];
  for (int c = tid; c < XC0; c += 512){
    float v = 0.f;
    if (c>=2 && c<4)       v = ball[b*2 + (c-2)];
    else if (c>=4 && c<36) v = remb[role*32 + (c-4)];
    _Float16 hv = (_Float16)v;
    x0[(size_t)n*XC0+c] = hv;
    x1[(size_t)n*XC0+c] = hv;
  }
  for (int c = tid; c < XC1; c += 512){
    hc0[(size_t)n*XC1+c] = (_Float16)0.f;
    hc1[(size_t)n*XC1+c] = (_Float16)0.f;
  }
  if (tid < 512){
    c0[n*512+tid]=0.f; c1[n*512+tid]=0.f;
  }
}

__global__ __launch_bounds__(128) void katt0(const float* __restrict__ ipos,
                                             const float* __restrict__ M,
                                             const float* __restrict__ S,
                                             const float* __restrict__ bv2,
                                             _Float16* __restrict__ x){
  int n = blockIdx.x, tid = threadIdx.x;
  float p0 = ipos[n*2], p1 = ipos[n*2+1];
  if (tid==0){ x[(size_t)n*XC0]=(_Float16)p0; x[(size_t)n*XC0+1]=(_Float16)p1; }
  float fa=p0*p0, fb=p0*p1, fc=p1*p1;
  for (int hd = tid; hd < 512; hd += 128){
    int h = hd>>7;
    int sb = n*24 + h*6;
    float den = S[sb] + p0*S[sb+1] + p1*S[sb+2] + fa*S[sb+3] + fb*S[sb+4] + fc*S[sb+5];
    const float* mp = M + (size_t)sb*128 + (hd&127);
    float num = mp[0] + p0*mp[128] + p1*mp[256] + fa*mp[384] + fb*mp[512] + fc*mp[640];
    x[(size_t)n*XC0 + 36 + hd] = (_Float16)(num/den + bv2[hd]);
  }
}

// ---------------- persistent loop kernel ----------------

struct KA {
  const _Float16 *hB0, *hB1, *hWf1;
  const float *fb0, *fb1, *bf1, *Wf2, *bf2, *fM, *fS, *fbv2;
  float *fc0, *fc1, *out;
  _Float16 *xc0, *xc1, *hc0, *hc1;
  unsigned *bar;
};

// monotonic grid barrier: NO fences, NO counter reset (ordering-hazard-free).
// Data visibility: producers' sc1 stores drain (vmcnt0 before s_barrier) to
// L3 before arrival atomics; consumers read via sc1 loads from L3.
__device__ __forceinline__ void gridbar(unsigned* cnt, unsigned* gen, unsigned* k){
  __syncthreads();
  if (threadIdx.x == 0){
    unsigned kk = ++(*k);
    unsigned a = __hip_atomic_fetch_add(cnt, 1u, __ATOMIC_RELAXED, __HIP_MEMORY_SCOPE_AGENT);
    if (a == kk*NBLK - 1u){
      __hip_atomic_store(gen, kk, __ATOMIC_RELAXED, __HIP_MEMORY_SCOPE_AGENT);
    } else {
      while (__hip_atomic_load(gen, __ATOMIC_RELAXED, __HIP_MEMORY_SCOPE_AGENT) < kk)
        __builtin_amdgcn_s_sleep(4);
    }
  }
  __syncthreads();
}

// One layer: gates = Acat @ Bcat^T + bias, fused LSTM.
// 256 blocks = 8 mblk (80 rows) x 32 jb (16 cols/gate); 4 waves = 4 gates.
// A (activations) via agent-atomic dword loads (L3-coherent); B (weights)
// plain cached (L2-hot). Reg prefetch distance 2, 2 LDS buffers.
__device__ __forceinline__ void gates_phase(
    const _Float16* __restrict__ A, int lda, int nc, const _Float16* __restrict__ B,
    const float* __restrict__ bias, float* __restrict__ cst,
    _Float16* __restrict__ h1p, int ldh1, int co1,
    _Float16* __restrict__ h2p, int ldh2, int co2,
    _Float16 (*sbuf)[10368], float (*eps)[80][17])
{
  int tid = threadIdx.x, w = tid>>6, lane = tid&63;
  int lr = lane&15, lq = lane>>4;
  int bx = blockIdx.x, mblk = bx>>5, jb = bx&31;
  int m0 = mblk*80, j0 = jb*16;
  int lda_dw = lda>>1;

  // A tile: 80 rows x 32 dwords; 2560 dwords, 10 per thread
  const unsigned* uA = (const unsigned*)A;
  unsigned abase[10];
  int aldi[10];
#pragma unroll
  for (int i=0;i<10;i++){
    int idx = tid + i*256;
    abase[i] = (unsigned)((m0 + (idx>>5))*lda_dw + (idx&31));
    aldi[i]  = (idx>>5)*36 + (idx&31);
  }
  // B tile: 64 rows (4 gates x 16 cols) x 64 halves; 2 hx8 per thread, plain
  int rB0 = tid>>3, rB1 = (tid+256)>>3;
  const _Float16* gB0 = B + (size_t)((rB0>>4)*512 + j0 + (rB0&15))*lda + (tid&7)*8;
  const _Float16* gB1 = B + (size_t)((rB1>>4)*512 + j0 + (rB1&15))*lda + (tid&7)*8;
  int sB0 = 5760 + rB0*72 + (tid&7)*8;
  int sB1 = 5760 + rB1*72 + (tid&7)*8;

  unsigned A0[10], A1[10];
  hx8 B00, B01, B10, B11;
#pragma unroll
  for (int i=0;i<10;i++) A0[i] = ald(uA + abase[i]);
  B00 = *(const hx8*)gB0;
  B01 = *(const hx8*)gB1;
#pragma unroll
  for (int i=0;i<10;i++) A1[i] = ald(uA + abase[i] + 32);
  B10 = *(const hx8*)(gB0 + 64);
  B11 = *(const hx8*)(gB1 + 64);

  fx4 ac[5];
#pragma unroll
  for (int s=0;s<5;s++) ac[s] = fx4{0.f,0.f,0.f,0.f};

  for (int c=0; c<nc; ++c){
    _Float16* sb = sbuf[c&1];
    unsigned* su = (unsigned*)sb;
    if ((c&1)==0){
#pragma unroll
      for (int i=0;i<10;i++) su[aldi[i]] = A0[i];
      *(hx8*)(sb+sB0) = B00;
      *(hx8*)(sb+sB1) = B01;
    } else {
#pragma unroll
      for (int i=0;i<10;i++) su[aldi[i]] = A1[i];
      *(hx8*)(sb+sB0) = B10;
      *(hx8*)(sb+sB1) = B11;
    }
    __syncthreads();
    if (c+2 < nc){
      unsigned koff = (unsigned)(c+2)*32;
      int kh = (c+2)*64;
      if ((c&1)==0){
#pragma unroll
        for (int i=0;i<10;i++) A0[i] = ald(uA + abase[i] + koff);
        B00 = *(const hx8*)(gB0 + kh);
        B01 = *(const hx8*)(gB1 + kh);
      } else {
#pragma unroll
        for (int i=0;i<10;i++) A1[i] = ald(uA + abase[i] + koff);
        B10 = *(const hx8*)(gB0 + kh);
        B11 = *(const hx8*)(gB1 + kh);
      }
    }
    const _Float16* bp = sb + 5760 + (w*16+lr)*72 + lq*8;
    hx8 b0 = *(const hx8*)bp;
    hx8 b1 = *(const hx8*)(bp+32);
#pragma unroll
    for (int s=0;s<5;s++){
      hx8 a0 = *(const hx8*)(sb + (s*16+lr)*72 + lq*8);
      ac[s] = __builtin_amdgcn_mfma_f32_16x16x32_f16(a0, b0, ac[s], 0,0,0);
    }
#pragma unroll
    for (int s=0;s<5;s++){
      hx8 a1 = *(const hx8*)(sb + (s*16+lr)*72 + lq*8 + 32);
      ac[s] = __builtin_amdgcn_mfma_f32_16x16x32_f16(a1, b1, ac[s], 0,0,0);
    }
  }
#pragma unroll
  for (int s=0;s<5;s++)
#pragma unroll
    for (int r=0;r<4;r++)
      eps[w][s*16+lq*4+r][lr] = ac[s][r];
  __syncthreads();
  // epilogue: 640 dword cells (80 rows x 8 j-pairs)
  float2* c2 = (float2*)cst;
  unsigned* uh1 = (unsigned*)h1p;
  unsigned* uh2 = (unsigned*)h2p;
  int ldh1d = ldh1>>1, ldh2d = ldh2>>1;
#pragma unroll
  for (int e=0;e<3;e++){
    int idx = e*256 + tid;
    if (idx < 640){
      int ml = idx>>3, jd = idx&7;
      int j = jd*2;
      float bi0 = bias[       j0+j], bi1 = bias[       j0+j+1];
      float bf0 = bias[ 512 + j0+j], bf1_ = bias[ 512 + j0+j+1];
      float bg0 = bias[1024 + j0+j], bg1 = bias[1024 + j0+j+1];
      float bo0 = bias[1536 + j0+j], bo1 = bias[1536 + j0+j+1];
      int ci = (m0+ml)*256 + (j0>>1) + jd;
      float2 cc_ = c2[ci];
      float gi0 = eps[0][ml][j] + bi0, gi1 = eps[0][ml][j+1] + bi1;
      float gf0 = eps[1][ml][j] + bf0, gf1 = eps[1][ml][j+1] + bf1_;
      float gg0 = eps[2][ml][j] + bg0, gg1 = eps[2][ml][j+1] + bg1;
      float go0 = eps[3][ml][j] + bo0, go1 = eps[3][ml][j+1] + bo1;
      float cn0 = sigm(gf0)*cc_.x + sigm(gi0)*tanh_(gg0);
      float cn1 = sigm(gf1)*cc_.y + sigm(gi1)*tanh_(gg1);
      float hn0 = sigm(go0)*tanh_(cn0);
      float hn1 = sigm(go1)*tanh_(cn1);
      c2[ci] = float2{cn0, cn1};
      unsigned hu = packh(hn0, hn1);
      ast(uh1 + (size_t)(m0+ml)*ldh1d + ((co1+j0)>>1) + jd, hu);
      if (h2p) ast(uh2 + (size_t)(m0+ml)*ldh2d + ((co2+j0)>>1) + jd, hu);
    }
  }
}

// head (Wf1/relu/Wf2) + next-step attention; blocks 0..39, 16 rows each
__device__ __forceinline__ void head_phase(const _Float16* __restrict__ h1,
    const _Float16* __restrict__ Wf1, const float* __restrict__ bf1,
    const float* __restrict__ Wf2, const float* __restrict__ bf2,
    const float* __restrict__ M, const float* __restrict__ S,
    const float* __restrict__ bv2, _Float16* __restrict__ xn,
    float* __restrict__ out, int t,
    float* hidp, float (*posL)[2], float (*denL)[4])
{
  int tid = threadIdx.x, w = tid>>6, lane = tid&63;
  int lr = lane&15, lq = lane>>4;
  int n0 = blockIdx.x*16;
  const unsigned* uh = (const unsigned*)h1;
  unsigned* uxn = (unsigned*)xn;
  fx4 a0=fx4{0.f,0.f,0.f,0.f}, a1=a0, a2=a0, a3=a0;
  {
    unsigned hbase = (unsigned)((n0+lr)*512 + lq*4);
    const _Float16* bp0 = Wf1 + (size_t)(w*64 + lr)*512 + lq*8;
    const _Float16* bp1 = bp0 + 16*512;
    const _Float16* bp2 = bp0 + 32*512;
    const _Float16* bp3 = bp0 + 48*512;
    for (int ks=0; ks<16; ks++){
      int k = ks*32;
      ux4 av;
      av.x = ald(uh + hbase + ks*16 + 0);
      av.y = ald(uh + hbase + ks*16 + 1);
      av.z = ald(uh + hbase + ks*16 + 2);
      av.w = ald(uh + hbase + ks*16 + 3);
      hx8 a = __builtin_bit_cast(hx8, av);
      a0 = __builtin_amdgcn_mfma_f32_16x16x32_f16(a, *(const hx8*)(bp0+k), a0, 0,0,0);
      a1 = __builtin_amdgcn_mfma_f32_16x16x32_f16(a, *(const hx8*)(bp1+k), a1, 0,0,0);
      a2 = __builtin_amdgcn_mfma_f32_16x16x32_f16(a, *(const hx8*)(bp2+k), a2, 0,0,0);
      a3 = __builtin_amdgcn_mfma_f32_16x16x32_f16(a, *(const hx8*)(bp3+k), a3, 0,0,0);
    }
  }
#pragma unroll
  for (int r=0;r<4;r++){
    int row = lq*4+r;
    hidp[row*264 + w*64 +  0 + lr] = fmaxf(a0[r] + bf1[w*64 +  0 + lr], 0.f);
    hidp[row*264 + w*64 + 16 + lr] = fmaxf(a1[r] + bf1[w*64 + 16 + lr], 0.f);
    hidp[row*264 + w*64 + 32 + lr] = fmaxf(a2[r] + bf1[w*64 + 32 + lr], 0.f);
    hidp[row*264 + w*64 + 48 + lr] = fmaxf(a3[r] + bf1[w*64 + 48 + lr], 0.f);
  }
  __syncthreads();
  {
    int nn = tid>>4, o = (tid>>3)&1, sub = tid&7;
    float s = 0.f;
    for (int k2=0;k2<32;k2++) s += hidp[nn*264 + k2*8 + sub] * Wf2[o*256 + k2*8 + sub];
    s += __shfl_xor(s, 1, 64);
    s += __shfl_xor(s, 2, 64);
    s += __shfl_xor(s, 4, 64);
    if (sub==0){
      s += bf2[o];
      out[((size_t)(n0+nn)*TSTEPS + t)*2 + o] = s;
      posL[nn][o] = s;
    }
  }
  __syncthreads();
  if (tid < 64){
    int nn = tid>>2, h = tid&3;
    float p0 = posL[nn][0], p1 = posL[nn][1];
    int sb = (n0+nn)*24 + h*6;
    float den = S[sb] + p0*S[sb+1] + p1*S[sb+2] + p0*p0*S[sb+3] + p0*p1*S[sb+4] + p1*p1*S[sb+5];
    denL[nn][h] = 1.0f/den;
    if (h==0) ast(uxn + (size_t)(n0+nn)*(XC0/2), packh(p0, p1));
  }
  __syncthreads();
  int h = tid>>6, d0 = (tid*2)&127;
  for (int nn=0; nn<16; nn++){
    float p0 = posL[nn][0], p1 = posL[nn][1];
    float fa = p0*p0, fb = p0*p1, fcx = p1*p1;
    const float* mp = M + (size_t)((n0+nn)*24 + h*6)*128 + d0;
    float n0v = mp[0] + p0*mp[128] + p1*mp[256] + fa*mp[384] + fb*mp[512] + fcx*mp[640];
    float n1v = mp[1] + p0*mp[129] + p1*mp[257] + fa*mp[385] + fb*mp[513] + fcx*mp[641];
    float dd = denL[nn][h];
    unsigned u = packh(n0v*dd + bv2[tid*2], n1v*dd + bv2[tid*2+1]);
    ast(uxn + (size_t)(n0+nn)*(XC0/2) + 18 + tid, u);
  }
}

__global__ __launch_bounds__(256) void kloop(KA a){
  __shared__ _Float16 sbuf[2][10368];  // A 80x72 @0, B 64x72 @5760 (halves)
  __shared__ float eps[4][80][17];     // gate exchange; head reuses as hid
  __shared__ float posL[16][2];
  __shared__ float denL[16][4];
  unsigned* cnt = a.bar;
  unsigned* gen = a.bar + 16;
  unsigned bk = 0;
  for (int t = 0; t < TSTEPS; ++t){
    _Float16* xin = (t&1) ? a.xc1 : a.xc0;
    _Float16* xnx = (t&1) ? a.xc0 : a.xc1;
    _Float16* hin = (t&1) ? a.hc1 : a.hc0;
    _Float16* hnx = (t&1) ? a.hc0 : a.hc1;
    gates_phase(xin, XC0, 17, a.hB0, a.fb0, a.fc0,
                hin, XC1, 0, xnx, XC0, 576, sbuf, eps);
    gridbar(cnt, gen, &bk);
    gates_phase(hin, XC1, 16, a.hB1, a.fb1, a.fc1,
                hnx, XC1, 512, (_Float16*)nullptr, 0, 0, sbuf, eps);
    gridbar(cnt, gen, &bk);
    if (blockIdx.x < 40)
      head_phase(hnx + 512, a.hWf1, a.bf1, a.Wf2, a.bf2, a.fM, a.fS, a.fbv2,
                 xnx, a.out, t, &eps[0][0][0], posL, denL);
    gridbar(cnt, gen, &bk);
  }
}

// ---------------------------------------------------------------------------

extern "C" void kernel_launch(void* const* d_in, const int* in_sizes, int n_in,
                              void* d_out, int out_size, void* d_ws, size_t ws_size,
                              hipStream_t stream) {
  const float* ctx   = (const float*)d_in[0];
  const float* ipos  = (const float*)d_in[1];
  const float* ball  = (const float*)d_in[2];
  const int*   roles = (const int*)  d_in[3];
  const float* remb  = (const float*)d_in[5];
  const float* Wc    = (const float*)d_in[6];
  const float* bc    = (const float*)d_in[7];
  const float* Wq    = (const float*)d_in[8];
  const float* bq    = (const float*)d_in[9];
  const float* Wk    = (const float*)d_in[10];
  const float* bk    = (const float*)d_in[11];
  const float* Wv    = (const float*)d_in[12];
  const float* bv    = (const float*)d_in[13];
  const float* Wo    = (const float*)d_in[14];
  const float* bo    = (const float*)d_in[15];
  const float* Wih0  = (const float*)d_in[16];
  const float* Whh0  = (const float*)d_in[17];
  const float* bih0  = (const float*)d_in[18];
  const float* bhh0  = (const float*)d_in[19];
  const float* Wih1  = (const float*)d_in[20];
  const float* Whh1  = (const float*)d_in[21];
  const float* bih1  = (const float*)d_in[22];
  const float* bhh1  = (const float*)d_in[23];
  const float* Wf1   = (const float*)d_in[24];
  const float* bf1   = (const float*)d_in[25];
  const float* Wf2   = (const float*)d_in[26];
  const float* bf2   = (const float*)d_in[27];
  float* out = (float*)d_out;

  char* w = (char*)d_ws;
  auto alloc = [&](size_t bytes){ void* p = (void*)w; w += (bytes + 255) & ~(size_t)255; return p; };
  float* fY    = (float*)alloc(12*512*4);
  float* fcc   = (float*)alloc(12*4);
  float* fu    = (float*)alloc(3*512*4);
  float* fz    = (float*)alloc(12*512*4);
  float* fbv2  = (float*)alloc(512*4);
  float* fWcv  = (float*)alloc((size_t)512*512*4);
  float* fWcvT = (float*)alloc((size_t)512*512*4);
  float* fWmix = (float*)alloc((size_t)2048*512*4);
  _Float16* hB0  = (_Float16*)alloc((size_t)2048*XC0*2);
  _Float16* hB1  = (_Float16*)alloc((size_t)2048*XC1*2);
  _Float16* hWf1 = (_Float16*)alloc((size_t)256*512*2);
  float* fb0 = (float*)alloc(2048*4);
  float* fb1 = (float*)alloc(2048*4);
  float* fW6 = (float*)alloc((size_t)NSEQ*24*200*4);
  float* fS  = (float*)alloc((size_t)NSEQ*24*4);
  float* fF  = (float*)alloc((size_t)NSEQ*24*512*4);
  float* fM  = (float*)alloc((size_t)NSEQ*24*128*4);
  _Float16* xc0 = (_Float16*)alloc((size_t)NSEQ*XC0*2);
  _Float16* xc1 = (_Float16*)alloc((size_t)NSEQ*XC0*2);
  _Float16* hc0 = (_Float16*)alloc((size_t)NSEQ*XC1*2);
  _Float16* hc1 = (_Float16*)alloc((size_t)NSEQ*XC1*2);
  float* fc0 = (float*)alloc((size_t)NSEQ*512*4);
  float* fc1 = (float*)alloc((size_t)NSEQ*512*4);
  unsigned* bar = (unsigned*)alloc(256);

  // ---- folds ----
  kF1 <<<2,  256, 0, stream>>>(Wq, Wc, bc, bq, fu);
  kF2a<<<12, 512, 0, stream>>>(Wk, fu, fz);
  kF2b<<<12, 512, 0, stream>>>(fz, Wc, bc, bk, fu, fY, fcc);
  kFbv<<<2,  256, 0, stream>>>(Wv, bc, bv, fbv2);
  kgemm<<<dim3(8,8),  256, 0, stream>>>(Wv,   512, 0,  Wc, 512, fWcv,  512, 512);
  ktransp<<<1024, 256, 0, stream>>>(fWcv, fWcvT);
  kgemm<<<dim3(8,32), 256, 0, stream>>>(Wih0, 548, 36, Wo, 512, fWmix, 512, 512);
  kbcat0<<<2048, 256, 0, stream>>>(Wih0, fWmix, Whh0, hB0);
  kbcat1<<<2048, 256, 0, stream>>>(Wih1, Whh1, hB1);
  kcast<<<512,  256, 0, stream>>>(Wf1, hWf1, 256*512);
  kbias<<<8, 256, 0, stream>>>(Wih0, bo, bih0, bhh0, bih1, bhh1, fb0, fb1);

  // ---- moments ----
  kP1<<<NSEQ, 256, 0, stream>>>(ctx, fY, fcc, fW6);
  kP2<<<NSEQ, 256, 0, stream>>>(ctx, fW6, fF, fS);
  kP3<<<NSEQ*4, 128, 0, stream>>>(fF, fWcvT, fM);

  // ---- state init ----
  kinit<<<NSEQ, 512, 0, stream>>>(ball, roles, remb, xc0, xc1, hc0, hc1, fc0, fc1);
  katt0<<<NSEQ, 128, 0, stream>>>(ipos, fM, fS, fbv2, xc0);

  // ---- persistent recurrent loop ----
  hipMemsetAsync(bar, 0, 128, stream);
  KA ka;
  ka.hB0=hB0; ka.hB1=hB1; ka.hWf1=hWf1;
  ka.fb0=fb0; ka.fb1=fb1; ka.bf1=bf1; ka.Wf2=Wf2; ka.bf2=bf2;
  ka.fM=fM; ka.fS=fS; ka.fbv2=fbv2;
  ka.fc0=fc0; ka.fc1=fc1; ka.out=out;
  ka.xc0=xc0; ka.xc1=xc1; ka.hc0=hc0; ka.hc1=hc1;
  ka.bar=bar;
  kloop<<<NBLK, 256, 0, stream>>>(ka);
}